// Round 1
// baseline (162.978 us; speedup 1.0000x reference)
//
#include <hip/hip_runtime.h>
#include <hip/hip_cooperative_groups.h>

namespace cg = cooperative_groups;

constexpr int BSZ = 512;
constexpr int DIM = 128;
constexpr int NREG = 6;                 // 6*64 = 384 register-cached negative slots
#define MARGIN_F 0.2f
#define EPS_F 1e-6f

// Single cooperative kernel, 512 blocks x 256 threads, all co-resident
// (2 blocks/CU; ~30 KB LDS, VGPR-capped by launch_bounds).
//
// Phase A: D[i,j] = ||f_i - f_j + eps||_2 in 32x16 tiles (16 x 32 tile grid ->
//   512 blocks, 2 blocks/CU = 2x the latency hiding of the old 256-block
//   32x32 version). 512 blocks x 24 KB coalesced feat reads = 12 MB, L2-hit
//   after first touch.
// grid.sync()
// Phase B: one block per anchor (256 thr handle 2 columns each). Ballot-
//   compaction identical in ordering to the old 512-thread kernel (halves
//   h-major). Register-cached negatives vs LDS-broadcast positives.
// grid.sync()
// Block 0 inlines the old finalize kernel (removes a full launch boundary +
//   exposed single-block latency).
__global__ __launch_bounds__(256, 2) void triplet_fused(
    const float* __restrict__ feat, const int* __restrict__ mask,
    float* __restrict__ D, double* __restrict__ num_part,
    int* __restrict__ den_part, float* __restrict__ out) {
  const int tid = threadIdx.x;
  const int wave = tid >> 6;
  const int lane = tid & 63;

  // Phase A shared (25.3 KB)
  __shared__ float4 At[32][33];         // pitch 33 breaks bank aliasing
  __shared__ float4 Bt[16][33];
  // Phase B shared (4.2 KB)
  __shared__ float apos[BSZ];           // compacted positives (+margin), pad -1e30
  __shared__ float bneg[BSZ];           // compacted negatives, padded w/ +1e30
  __shared__ int wt[8][2];
  __shared__ float wred[4];
  __shared__ double sn[4];
  __shared__ long long sd[4];

  cg::grid_group grid = cg::this_grid();

  // ---------------- Phase A: distance tile 32 rows x 16 cols ----------------
  {
    const int bi = blockIdx.x >> 5;     // 0..15  (32-row tile)
    const int bj = blockIdx.x & 31;     // 0..31  (16-col tile)
    const float4* ga = (const float4*)feat + (size_t)bi * 32 * (DIM / 4);
    const float4* gb = (const float4*)feat + (size_t)bj * 16 * (DIM / 4);
#pragma unroll
    for (int k = 0; k < 4; ++k) {
      const int idx = tid + k * 256;    // 0..1023, coalesced
      float4 va = ga[idx];
      va.x += EPS_F; va.y += EPS_F; va.z += EPS_F; va.w += EPS_F;
      At[idx >> 5][idx & 31] = va;      // EPS folded: (a+eps)-b == a-b+eps
    }
#pragma unroll
    for (int k = 0; k < 2; ++k) {
      const int idx = tid + k * 256;    // 0..511
      Bt[idx >> 5][idx & 31] = gb[idx];
    }
    __syncthreads();

    const int r0 = tid >> 4;            // 0..15
    const int c0 = tid & 15;            // 0..15
    float s0 = 0.f, s1 = 0.f;
#pragma unroll
    for (int d = 0; d < DIM / 4; ++d) {
      const float4 a0 = At[r0][d];      // 16-lane broadcast, conflict-free
      const float4 a1 = At[r0 + 16][d];
      const float4 b0 = Bt[c0][d];      // 2-way (free per m136)
      float x;
      x = a0.x - b0.x; s0 = fmaf(x, x, s0);
      x = a0.y - b0.y; s0 = fmaf(x, x, s0);
      x = a0.z - b0.z; s0 = fmaf(x, x, s0);
      x = a0.w - b0.w; s0 = fmaf(x, x, s0);
      x = a1.x - b0.x; s1 = fmaf(x, x, s1);
      x = a1.y - b0.y; s1 = fmaf(x, x, s1);
      x = a1.z - b0.z; s1 = fmaf(x, x, s1);
      x = a1.w - b0.w; s1 = fmaf(x, x, s1);
    }
    D[(size_t)(bi * 32 + r0) * BSZ + bj * 16 + c0]      = sqrtf(s0);
    D[(size_t)(bi * 32 + r0 + 16) * BSZ + bj * 16 + c0] = sqrtf(s1);
  }

  grid.sync();                          // D fully materialized + visible

  // ---------------- Phase B: one anchor per block ----------------
  const int i = blockIdx.x;
  {
    const float dist0 = D[(size_t)i * BSZ + tid];          // coalesced dword
    const float dist1 = D[(size_t)i * BSZ + tid + 256];
    const int m0 = mask[(size_t)i * BSZ + tid];
    const int m1 = mask[(size_t)i * BSZ + tid + 256];
    const bool p0 = (m0 != 0);
    const bool n0 = (m0 == 0) && (tid != i);
    const bool p1 = (m1 != 0);
    const bool n1 = (m1 == 0) && (tid + 256 != i);

    const unsigned long long bp0 = __ballot(p0);
    const unsigned long long bn0 = __ballot(n0);
    const unsigned long long bp1 = __ballot(p1);
    const unsigned long long bn1 = __ballot(n1);
    const unsigned long long ltm = (1ull << lane) - 1ull;
    if (lane == 0) {
      wt[wave][0]     = __popcll(bp0); wt[wave][1]     = __popcll(bn0);
      wt[4 + wave][0] = __popcll(bp1); wt[4 + wave][1] = __popcll(bn1);
    }
    __syncthreads();

    int pb0 = 0, nb0 = 0, pb1 = 0, nb1 = 0, nP = 0, nN = 0;
#pragma unroll
    for (int w = 0; w < 8; ++w) {
      const int tp = wt[w][0], tn = wt[w][1];
      if (w < wave)     { pb0 += tp; nb0 += tn; }
      if (w < 4 + wave) { pb1 += tp; nb1 += tn; }
      nP += tp; nN += tn;
    }
    if (p0)      apos[pb0 + __popcll(bp0 & ltm)] = dist0 + MARGIN_F;
    else if (n0) bneg[nb0 + __popcll(bn0 & ltm)] = dist0;
    if (p1)      apos[pb1 + __popcll(bp1 & ltm)] = dist1 + MARGIN_F;
    else if (n1) bneg[nb1 + __popcll(bn1 & ltm)] = dist1;

    const int nPpad = (nP + 31) & ~31;
    for (int j = nP + tid; j < nPpad; j += 256) apos[j] = -1e30f;    // relu -> 0
    for (int k = nN + tid; k < NREG * 64; k += 256) bneg[k] = 1e30f; // relu -> 0
    __syncthreads();

    float bnr[NREG];
#pragma unroll
    for (int r = 0; r < NREG; ++r) bnr[r] = bneg[lane + 64 * r];
    float acc[NREG];
#pragma unroll
    for (int r = 0; r < NREG; ++r) acc[r] = 0.f;

    const float4* apos4 = (const float4*)apos;
    const int nj4 = nPpad >> 2;
    for (int j4 = wave; j4 < nj4; j4 += 4) {
      const float4 a = apos4[j4];                    // uniform addr: LDS broadcast
#pragma unroll
      for (int r = 0; r < NREG; ++r) {
        acc[r] += fmaxf(a.x - bnr[r], 0.f);
        acc[r] += fmaxf(a.y - bnr[r], 0.f);
        acc[r] += fmaxf(a.z - bnr[r], 0.f);
        acc[r] += fmaxf(a.w - bnr[r], 0.f);
      }
    }
    float lsum = 0.f;
#pragma unroll
    for (int r = 0; r < NREG; ++r) lsum += acc[r];

    if (nN > NREG * 64) {                            // rare statistical tail
      for (int j = wave; j < nP; j += 4) {
        const float aj = apos[j];
        for (int k = NREG * 64 + lane; k < nN; k += 64)
          lsum += fmaxf(aj - bneg[k], 0.f);
      }
    }

    for (int off = 32; off > 0; off >>= 1) lsum += __shfl_down(lsum, off, 64);
    if (lane == 0) wred[wave] = lsum;
    __syncthreads();
    if (tid == 0) {
      const float bsum = wred[0] + wred[1] + wred[2] + wred[3];
      num_part[i] = (double)bsum;                    // distinct address per block
      den_part[i] = nP * nN;
    }
  }

  grid.sync();                          // partials visible

  // ---------------- Finalize (block 0 only) ----------------
  if (i == 0) {
    double n = 0.0;
    long long d = 0;
    for (int j = tid; j < BSZ; j += 256) {
      n += num_part[j];
      d += (long long)den_part[j];
    }
    for (int off = 32; off > 0; off >>= 1) {
      n += __shfl_down(n, off, 64);
      d += __shfl_down(d, off, 64);
    }
    if (lane == 0) { sn[wave] = n; sd[wave] = d; }
    __syncthreads();
    if (tid == 0) {
      const double N = sn[0] + sn[1] + sn[2] + sn[3];
      const long long Dn = sd[0] + sd[1] + sd[2] + sd[3];
      out[0] = (Dn > 0) ? (float)(N / (double)Dn) : 0.0f;
    }
  }
}

extern "C" void kernel_launch(void* const* d_in, const int* in_sizes, int n_in,
                              void* d_out, int out_size, void* d_ws, size_t ws_size,
                              hipStream_t stream) {
  const float* feat = (const float*)d_in[0];
  const int* mask = (const int*)d_in[1];
  float* out = (float*)d_out;

  float* Dm = (float*)d_ws;                                  // 512*512*4 = 1 MB
  double* num_part = (double*)((char*)d_ws + (1 << 20));
  int* den_part = (int*)((char*)d_ws + (1 << 20) + BSZ * sizeof(double));

  void* args[] = {(void*)&feat, (void*)&mask, (void*)&Dm,
                  (void*)&num_part, (void*)&den_part, (void*)&out};
  hipLaunchCooperativeKernel((const void*)triplet_fused, dim3(512), dim3(256),
                             args, 0, stream);
}

// Round 2
// 77.129 us; speedup vs baseline: 2.1131x; 2.1131x over previous
//
#include <hip/hip_runtime.h>

constexpr int BSZ = 512;
constexpr int DIM = 128;
constexpr int NREG = 6;                 // 6*64 = 384 register-cached negative slots
#define MARGIN_F 0.2f
#define EPS_F 1e-6f

// Fused kernel: block i = anchor i (512 blocks x 512 threads, 2 blocks/CU).
//
// Phase 1: compute D-row i on the fly from features (256 KB, L2-resident;
//   no D matrix in HBM, no separate dist kernel, no grid sync).
//   Coalesced: each wave instruction reads 2 consecutive feature rows
//   (64 lanes x float4 = 1 KB contiguous); each lane keeps its own anchor
//   chunk (+eps folded) in a register; 32-lane __shfl_xor reduce.
// Phase 2: verbatim round-0 triplet_main (ballot compaction, register-cached
//   negatives vs LDS-broadcast positives) — same summation order.
//
// NOTE (round-1 post-mortem): cooperative grid.sync() cost ~40 us per sync
// on a 512-block grid — 100x a kernel boundary. Stream-ordered dispatches
// only.
__global__ __launch_bounds__(512, 4) void triplet_fused2(
    const float* __restrict__ feat, const int* __restrict__ mask,
    double* __restrict__ num_part, int* __restrict__ den_part) {
  const int i = blockIdx.x;
  const int tid = threadIdx.x;
  const int wave = tid >> 6;
  const int lane = tid & 63;
  const int half = lane >> 5;           // which of the 2 rows this instr covers
  const int l31 = lane & 31;            // float4 slot within a row

  __shared__ float dist_sm[BSZ];        // this anchor's D-row
  __shared__ float apos[BSZ];           // compacted positives (+margin), pad -1e30
  __shared__ float bneg[BSZ];           // compacted negatives, padded w/ +1e30
  __shared__ int wtot[8][2];
  __shared__ float wred[8];

  // ---------------- Phase 1: D-row i from features ----------------
  {
    // anchor chunk dims [4*l31, 4*l31+3], EPS folded: (a+eps)-b == a-b+eps
    float4 fl = ((const float4*)feat)[i * 32 + l31];
    fl.x += EPS_F; fl.y += EPS_F; fl.z += EPS_F; fl.w += EPS_F;

    const float4* g = (const float4*)feat;
#pragma unroll
    for (int k = 0; k < 32; ++k) {
      const int row = wave * 64 + 2 * k + half;     // wave w covers rows [64w,64w+64)
      const float4 v = g[row * 32 + l31];           // 1 KB contiguous per wave
      float x, p;
      x = fl.x - v.x; p = x * x;
      x = fl.y - v.y; p = fmaf(x, x, p);
      x = fl.z - v.z; p = fmaf(x, x, p);
      x = fl.w - v.w; p = fmaf(x, x, p);
#pragma unroll
      for (int off = 16; off > 0; off >>= 1) p += __shfl_xor(p, off, 64);
      if (l31 == 0) dist_sm[row] = sqrtf(p);
    }
  }
  __syncthreads();

  // ---------------- Phase 2: triplet reduction (round-0 proven) ----------------
  const float dist = dist_sm[tid];
  const int m = mask[(size_t)i * BSZ + tid];        // coalesced dword
  const bool is_pos = (m != 0);
  const bool is_neg = (m == 0) && (tid != i);

  const unsigned long long bp = __ballot(is_pos);
  const unsigned long long bn = __ballot(is_neg);
  const unsigned long long ltm = (1ull << lane) - 1ull;
  const int p_before = __popcll(bp & ltm);
  const int n_before = __popcll(bn & ltm);
  if (lane == 0) { wtot[wave][0] = __popcll(bp); wtot[wave][1] = __popcll(bn); }
  __syncthreads();

  int pbase = 0, nbase = 0, nP = 0, nN = 0;
#pragma unroll
  for (int w = 0; w < 8; ++w) {
    const int tp = wtot[w][0], tn = wtot[w][1];
    if (w < wave) { pbase += tp; nbase += tn; }
    nP += tp; nN += tn;
  }
  if (is_pos)      apos[pbase + p_before] = dist + MARGIN_F;
  else if (is_neg) bneg[nbase + n_before] = dist;

  const int nPpad = (nP + 31) & ~31;
  { const int j = nP + tid; if (j < nPpad) apos[j] = -1e30f; }    // relu -> 0
  { const int k = nN + tid; if (k < NREG * 64) bneg[k] = 1e30f; } // relu -> 0
  __syncthreads();

  float bnr[NREG];
#pragma unroll
  for (int r = 0; r < NREG; ++r) bnr[r] = bneg[lane + 64 * r];

  float acc[NREG];
#pragma unroll
  for (int r = 0; r < NREG; ++r) acc[r] = 0.f;

  const float4* apos4 = (const float4*)apos;
  const int nj4 = nPpad >> 2;
  for (int j4 = wave; j4 < nj4; j4 += 8) {
    const float4 a = apos4[j4];                    // uniform addr: LDS broadcast
#pragma unroll
    for (int r = 0; r < NREG; ++r) {
      acc[r] += fmaxf(a.x - bnr[r], 0.f);
      acc[r] += fmaxf(a.y - bnr[r], 0.f);
      acc[r] += fmaxf(a.z - bnr[r], 0.f);
      acc[r] += fmaxf(a.w - bnr[r], 0.f);
    }
  }
  float lsum = 0.f;
#pragma unroll
  for (int r = 0; r < NREG; ++r) lsum += acc[r];

  if (nN > NREG * 64) {                            // rare statistical tail
    for (int j = wave; j < nP; j += 8) {
      const float aj = apos[j];
      for (int k = NREG * 64 + lane; k < nN; k += 64)
        lsum += fmaxf(aj - bneg[k], 0.f);
    }
  }

  for (int off = 32; off > 0; off >>= 1) lsum += __shfl_down(lsum, off, 64);
  if (lane == 0) wred[wave] = lsum;
  __syncthreads();
  if (tid == 0) {
    float bsum = 0.f;
#pragma unroll
    for (int w = 0; w < 8; ++w) bsum += wred[w];
    num_part[i] = (double)bsum;                    // distinct address per block
    den_part[i] = nP * nN;
  }
}

__global__ __launch_bounds__(256) void triplet_finalize(
    const double* __restrict__ num_part, const int* __restrict__ den_part,
    float* __restrict__ out) {
  const int tid = threadIdx.x;
  double n = 0.0;
  long long d = 0;
  for (int i = tid; i < BSZ; i += 256) {
    n += num_part[i];
    d += den_part[i];
  }
  __shared__ double sn[4];
  __shared__ long long sd[4];
  for (int off = 32; off > 0; off >>= 1) {
    n += __shfl_down(n, off, 64);
    d += __shfl_down(d, off, 64);
  }
  if ((tid & 63) == 0) { sn[tid >> 6] = n; sd[tid >> 6] = d; }
  __syncthreads();
  if (tid == 0) {
    const double N = sn[0] + sn[1] + sn[2] + sn[3];
    const long long Dn = sd[0] + sd[1] + sd[2] + sd[3];
    out[0] = (Dn > 0) ? (float)(N / (double)Dn) : 0.0f;
  }
}

extern "C" void kernel_launch(void* const* d_in, const int* in_sizes, int n_in,
                              void* d_out, int out_size, void* d_ws, size_t ws_size,
                              hipStream_t stream) {
  const float* feat = (const float*)d_in[0];
  const int* mask = (const int*)d_in[1];
  float* out = (float*)d_out;

  double* num_part = (double*)d_ws;                          // 512 * 8 B
  int* den_part = (int*)((char*)d_ws + BSZ * sizeof(double));

  triplet_fused2<<<BSZ, 512, 0, stream>>>(feat, mask, num_part, den_part);
  triplet_finalize<<<1, 256, 0, stream>>>(num_part, den_part, out);
}